// Round 3
// baseline (314.982 us; speedup 1.0000x reference)
//
#include <hip/hip_runtime.h>
#include <hip/hip_bf16.h>

#define LROWS 50000
#define KNN 32
#define DIM 128
#define TAU_INV 5.0f
#define EPS_NORM 1e-8f

// ---------------------------------------------------------------------------
// Kernel 1: fused projection  Q = H @ Wq^T,  Km = H @ Wk^T
// Block = 256 threads, 16 H-rows staged in LDS (8 KB).
// Thread t owns one output column: t < 128 -> Q col t, t >= 128 -> Km col t-128.
// ---------------------------------------------------------------------------
__global__ __launch_bounds__(256) void proj_kernel(
    const float* __restrict__ H,
    const float* __restrict__ Wq,
    const float* __restrict__ Wk,
    float* __restrict__ Q,
    float* __restrict__ Km) {
  __shared__ float Hs[16][DIM];
  const int tid = threadIdx.x;
  const int row0 = blockIdx.x * 16;

  {
    const float4* Hg = (const float4*)(H + (size_t)row0 * DIM);
    float4* Hs4 = (float4*)&Hs[0][0];
    Hs4[tid] = Hg[tid];
    Hs4[tid + 256] = Hg[tid + 256];
  }
  __syncthreads();

  const int c = tid;
  const float4* W4 =
      (c < DIM) ? (const float4*)(Wq + (size_t)c * DIM)
                : (const float4*)(Wk + (size_t)(c - DIM) * DIM);

  float acc[16];
#pragma unroll
  for (int r = 0; r < 16; ++r) acc[r] = 0.0f;

#pragma unroll 8
  for (int j4 = 0; j4 < DIM / 4; ++j4) {
    const float4 w = W4[j4];
    const int j = j4 * 4;
#pragma unroll
    for (int r = 0; r < 16; ++r) {
      float a = fmaf(Hs[r][j + 0], w.x, acc[r]);
      a = fmaf(Hs[r][j + 1], w.y, a);
      a = fmaf(Hs[r][j + 2], w.z, a);
      acc[r] = fmaf(Hs[r][j + 3], w.w, a);
    }
  }

  float* out = (c < DIM) ? Q : Km;
  const int cc = c & (DIM - 1);
#pragma unroll
  for (int r = 0; r < 16; ++r) {
    out[(size_t)(row0 + r) * DIM + cc] = acc[r];
  }
}

// ---------------------------------------------------------------------------
// Kernel 2: gathered dot + softmax(K=32) + mix + row-normalize + COO emit.
// Block = 256 threads = 8 rows; 32 lanes per row -> shfl_xor width-32 reduce.
// Outputs are FLOAT32: [vals | rows | cols], each L*K elements.
// ---------------------------------------------------------------------------
__global__ __launch_bounds__(256) void attn_kernel(
    const float* __restrict__ Q,
    const float* __restrict__ Km,
    const float* __restrict__ mixp,
    const float* __restrict__ knn_w,
    const int* __restrict__ knn_idx,
    float* __restrict__ vals,
    float* __restrict__ rows,
    float* __restrict__ cols) {
  const int tid = threadIdx.x;
  const int k = tid & 31;           // neighbor slot
  const int rloc = tid >> 5;        // 0..7 row within block
  const int l = blockIdx.x * 8 + rloc;

  const int o = l * KNN + k;
  const int idx = knn_idx[o];

  const float4* q4 = (const float4*)(Q + (size_t)l * DIM);
  const float4* k4 = (const float4*)(Km + (size_t)idx * DIM);

  float acc = 0.0f;
#pragma unroll
  for (int j = 0; j < DIM / 4; ++j) {
    const float4 a = q4[j];
    const float4 b = k4[j];
    acc = fmaf(a.x, b.x, acc);
    acc = fmaf(a.y, b.y, acc);
    acc = fmaf(a.z, b.z, acc);
    acc = fmaf(a.w, b.w, acc);
  }
  const float sim = acc * TAU_INV;

  // Softmax over the 32 lanes of this row.
  float m = sim;
#pragma unroll
  for (int off = 16; off > 0; off >>= 1)
    m = fmaxf(m, __shfl_xor(m, off, 32));
  const float e = expf(sim - m);
  float s = e;
#pragma unroll
  for (int off = 16; off > 0; off >>= 1)
    s += __shfl_xor(s, off, 32);
  const float A = e / s;

  const float mix = mixp[0];
  const float beta = 1.0f / (1.0f + expf(-mix));
  float w = (1.0f - beta) * knn_w[o] + beta * A;

  float ws = w;
#pragma unroll
  for (int off = 16; off > 0; off >>= 1)
    ws += __shfl_xor(ws, off, 32);
  const float v = w / (ws + EPS_NORM);

  vals[o] = v;
  rows[o] = (float)l;
  cols[o] = (float)idx;
}

extern "C" void kernel_launch(void* const* d_in, const int* in_sizes, int n_in,
                              void* d_out, int out_size, void* d_ws, size_t ws_size,
                              hipStream_t stream) {
  const float* H = (const float*)d_in[0];
  const float* Wq = (const float*)d_in[1];
  const float* Wk = (const float*)d_in[2];
  const float* mix = (const float*)d_in[3];
  const float* knn_w = (const float*)d_in[4];
  const int* knn_idx = (const int*)d_in[5];

  float* Qw = (float*)d_ws;                       // L*DIM f32 = 25.6 MB
  float* Kw = Qw + (size_t)LROWS * DIM;           // L*DIM f32 = 25.6 MB

  float* out = (float*)d_out;
  float* vals = out;
  float* rows = out + (size_t)LROWS * KNN;
  float* cols = out + 2 * (size_t)LROWS * KNN;

  proj_kernel<<<LROWS / 16, 256, 0, stream>>>(H, Wq, Wk, Qw, Kw);
  attn_kernel<<<LROWS / 8, 256, 0, stream>>>(Qw, Kw, mix, knn_w, knn_idx,
                                             vals, rows, cols);
}

// Round 4
// 216.387 us; speedup vs baseline: 1.4556x; 1.4556x over previous
//
#include <hip/hip_runtime.h>
#include <hip/hip_bf16.h>

#define LROWS 50000
#define KNN 32
#define DIM 128
#define TAU_INV 5.0f
#define EPS_NORM 1e-8f

typedef short s8v __attribute__((ext_vector_type(8)));
typedef float f32x4 __attribute__((ext_vector_type(4)));

__device__ __forceinline__ unsigned short f2bf(float f) {
  union { float f; unsigned u; } v; v.f = f;
  unsigned r = v.u + 0x7FFFu + ((v.u >> 16) & 1u);
  return (unsigned short)(r >> 16);
}
__device__ __forceinline__ float bf2f(unsigned short s) {
  union { unsigned u; float f; } v; v.u = ((unsigned)s) << 16;
  return v.f;
}

// ---------------------------------------------------------------------------
// Kernel A: Mt[c][k] = M[k][c],  M = Wq^T @ Wk  (so Mt = Wk^T @ Wq).
// Grid 128 blocks (c), 128 threads (k). Weights are L2-hot (128 KB).
// ---------------------------------------------------------------------------
__global__ __launch_bounds__(128) void mmat_kernel(
    const float* __restrict__ Wq, const float* __restrict__ Wk,
    unsigned short* __restrict__ Mt) {
  const int c = blockIdx.x;
  const int k = threadIdx.x;
  float acc = 0.f;
#pragma unroll 8
  for (int j = 0; j < DIM; ++j)
    acc = fmaf(Wk[j * DIM + c], Wq[j * DIM + k], acc);
  Mt[c * DIM + k] = f2bf(acc);
}

// ---------------------------------------------------------------------------
// Kernel B: G = Hb @ M  via MFMA 16x16x32 bf16; also emits Hb (bf16 copy of H).
// Block = 256 thr (4 waves), 64 H-rows staged as bf16 in LDS (16 KB).
// Wave w computes all 64 rows x cols [32w, 32w+32). B-frags (Mt) in registers.
// A: lane holds A[row=l&15][k=(l>>4)*8+j]; B: B[k=(l>>4)*8+j][col=l&15];
// D: D[row=(l>>4)*4+i][col=l&15]   (m89/m91-verified layouts).
// ---------------------------------------------------------------------------
__global__ __launch_bounds__(256) void proj_kernel(
    const float* __restrict__ H, const unsigned short* __restrict__ Mt,
    float* __restrict__ G, unsigned short* __restrict__ Hb) {
  __shared__ short Hs[64 * DIM];  // 16 KB bf16
  const int tid = threadIdx.x;
  const int row0 = blockIdx.x * 64;
  const int nrows = min(64, LROWS - row0);

  // Stage H tile -> bf16 LDS + Hb global (coalesced 16B chunks).
#pragma unroll
  for (int i = 0; i < 4; ++i) {
    const int cid = i * 256 + tid;   // 1024 chunks of 8 elems
    const int r = cid >> 4;          // local row 0..63
    const int cc = (cid & 15) * 8;   // col 0..120
    const int gr = (r < nrows) ? r : 0;  // clamp OOB rows (tail block)
    const float4* src = (const float4*)(H + (size_t)(row0 + gr) * DIM + cc);
    const float4 a = src[0], b = src[1];
    s8v p;
    p[0] = (short)f2bf(a.x); p[1] = (short)f2bf(a.y);
    p[2] = (short)f2bf(a.z); p[3] = (short)f2bf(a.w);
    p[4] = (short)f2bf(b.x); p[5] = (short)f2bf(b.y);
    p[6] = (short)f2bf(b.z); p[7] = (short)f2bf(b.w);
    *(s8v*)&Hs[cid * 8] = p;
    if (r < nrows)
      *(s8v*)(Hb + (size_t)(row0 + r) * DIM + cc) = p;
  }
  __syncthreads();

  const int lane = tid & 63;
  const int wv = tid >> 6;
  const int col0 = wv * 32;
  const int lr = lane & 15;
  const int lg = lane >> 4;

  // B-frags: Mt row-major [c][k] -> B[k][c]; 8 frags in regs (32 VGPR).
  s8v bfrag[2][4];
#pragma unroll
  for (int nt = 0; nt < 2; ++nt)
#pragma unroll
    for (int kk = 0; kk < 4; ++kk)
      bfrag[nt][kk] =
          *(const s8v*)(Mt + (col0 + nt * 16 + lr) * DIM + kk * 32 + lg * 8);

  f32x4 acc[4][2];
#pragma unroll
  for (int rt = 0; rt < 4; ++rt)
#pragma unroll
    for (int nt = 0; nt < 2; ++nt)
      acc[rt][nt] = (f32x4){0.f, 0.f, 0.f, 0.f};

#pragma unroll
  for (int rt = 0; rt < 4; ++rt) {
#pragma unroll
    for (int kk = 0; kk < 4; ++kk) {
      const s8v afrag =
          *(const s8v*)&Hs[(rt * 16 + lr) * DIM + kk * 32 + lg * 8];
#pragma unroll
      for (int nt = 0; nt < 2; ++nt)
        acc[rt][nt] = __builtin_amdgcn_mfma_f32_16x16x32_bf16(
            afrag, bfrag[nt][kk], acc[rt][nt], 0, 0, 0);
    }
  }

#pragma unroll
  for (int rt = 0; rt < 4; ++rt)
#pragma unroll
    for (int nt = 0; nt < 2; ++nt)
#pragma unroll
      for (int i = 0; i < 4; ++i) {
        const int r = rt * 16 + lg * 4 + i;
        if (r < nrows)
          G[(size_t)(row0 + r) * DIM + col0 + nt * 16 + lr] = acc[rt][nt][i];
      }
}

// ---------------------------------------------------------------------------
// Kernel C: sim[l,k] = <G[l], Hb[idx]> ; softmax(K=32) + mix + norm + COO.
// Gathered rows are bf16 (256 B = 2 cache lines). G row broadcast in-wave.
// ---------------------------------------------------------------------------
__global__ __launch_bounds__(256) void attn_kernel(
    const float* __restrict__ G, const unsigned short* __restrict__ Hb,
    const float* __restrict__ mixp, const float* __restrict__ knn_w,
    const int* __restrict__ knn_idx,
    float* __restrict__ vals, float* __restrict__ rows,
    float* __restrict__ cols) {
  const int tid = threadIdx.x;
  const int k = tid & 31;
  const int rloc = tid >> 5;
  const int l = blockIdx.x * 8 + rloc;

  const int o = l * KNN + k;
  const int idx = knn_idx[o];

  const s8v* k8 = (const s8v*)(Hb + (size_t)idx * DIM);
  const float4* g4 = (const float4*)(G + (size_t)l * DIM);

  float acc = 0.f;
#pragma unroll
  for (int j = 0; j < DIM / 8; ++j) {
    const s8v b = k8[j];
    const float4 g0 = g4[2 * j], g1 = g4[2 * j + 1];
    acc = fmaf(g0.x, bf2f((unsigned short)b[0]), acc);
    acc = fmaf(g0.y, bf2f((unsigned short)b[1]), acc);
    acc = fmaf(g0.z, bf2f((unsigned short)b[2]), acc);
    acc = fmaf(g0.w, bf2f((unsigned short)b[3]), acc);
    acc = fmaf(g1.x, bf2f((unsigned short)b[4]), acc);
    acc = fmaf(g1.y, bf2f((unsigned short)b[5]), acc);
    acc = fmaf(g1.z, bf2f((unsigned short)b[6]), acc);
    acc = fmaf(g1.w, bf2f((unsigned short)b[7]), acc);
  }
  const float sim = acc * TAU_INV;

  float m = sim;
#pragma unroll
  for (int off = 16; off > 0; off >>= 1)
    m = fmaxf(m, __shfl_xor(m, off, 32));
  const float e = expf(sim - m);
  float s = e;
#pragma unroll
  for (int off = 16; off > 0; off >>= 1)
    s += __shfl_xor(s, off, 32);
  const float A = e / s;

  const float beta = 1.0f / (1.0f + expf(-mixp[0]));
  float w = (1.0f - beta) * knn_w[o] + beta * A;

  float ws = w;
#pragma unroll
  for (int off = 16; off > 0; off >>= 1)
    ws += __shfl_xor(ws, off, 32);
  const float v = w / (ws + EPS_NORM);

  vals[o] = v;
  rows[o] = (float)l;
  cols[o] = (float)idx;
}

extern "C" void kernel_launch(void* const* d_in, const int* in_sizes, int n_in,
                              void* d_out, int out_size, void* d_ws, size_t ws_size,
                              hipStream_t stream) {
  const float* H = (const float*)d_in[0];
  const float* Wq = (const float*)d_in[1];
  const float* Wk = (const float*)d_in[2];
  const float* mix = (const float*)d_in[3];
  const float* knn_w = (const float*)d_in[4];
  const int* knn_idx = (const int*)d_in[5];

  unsigned short* Hb = (unsigned short*)d_ws;                      // 12.8 MB
  float* G = (float*)((char*)d_ws + (size_t)LROWS * DIM * 2);      // 25.6 MB
  unsigned short* Mt =
      (unsigned short*)((char*)d_ws + (size_t)LROWS * DIM * 6);    // 32 KB

  float* out = (float*)d_out;
  float* vals = out;
  float* rowsp = out + (size_t)LROWS * KNN;
  float* colsp = out + 2 * (size_t)LROWS * KNN;

  mmat_kernel<<<DIM, DIM, 0, stream>>>(Wq, Wk, Mt);
  proj_kernel<<<(LROWS + 63) / 64, 256, 0, stream>>>(H, Mt, G, Hb);
  attn_kernel<<<LROWS / 8, 256, 0, stream>>>(G, Hb, mix, knn_w, knn_idx,
                                             vals, rowsp, colsp);
}

// Round 5
// 162.966 us; speedup vs baseline: 1.9328x; 1.3278x over previous
//
#include <hip/hip_runtime.h>
#include <hip/hip_bf16.h>

#define LROWS 50000
#define KNN 32
#define DIM 128
#define TAU_INV 5.0f
#define EPS_NORM 1e-8f

typedef short s8v __attribute__((ext_vector_type(8)));
typedef float f32x4 __attribute__((ext_vector_type(4)));
typedef float f32x2 __attribute__((ext_vector_type(2)));
typedef int i32x2 __attribute__((ext_vector_type(2)));
typedef int i32x4 __attribute__((ext_vector_type(4)));

__device__ __forceinline__ unsigned short f2bf(float f) {
  union { float f; unsigned u; } v; v.f = f;
  unsigned r = v.u + 0x7FFFu + ((v.u >> 16) & 1u);
  return (unsigned short)(r >> 16);
}

// ---------------------------------------------------------------------------
// Kernel A: Mt[c][k] = (Wq^T Wk)^T[c][k] = sum_j Wk[j][c] * Wq[j][k], bf16.
// ---------------------------------------------------------------------------
__global__ __launch_bounds__(128) void mmat_kernel(
    const float* __restrict__ Wq, const float* __restrict__ Wk,
    unsigned short* __restrict__ Mt) {
  const int c = blockIdx.x;
  const int k = threadIdx.x;
  float acc = 0.f;
#pragma unroll 8
  for (int j = 0; j < DIM; ++j)
    acc = fmaf(Wk[j * DIM + c], Wq[j * DIM + k], acc);
  Mt[c * DIM + k] = f2bf(acc);
}

// ---------------------------------------------------------------------------
// Kernel B: G = H @ M via MFMA 16x16x32 bf16; emits Hb8 (fp8 e4m3 copy of H).
// Block = 256 thr (4 waves), 64 H-rows staged as bf16 in LDS (16 KB).
// ---------------------------------------------------------------------------
__global__ __launch_bounds__(256) void proj_kernel(
    const float* __restrict__ H, const unsigned short* __restrict__ Mt,
    float* __restrict__ G, unsigned char* __restrict__ Hb8) {
  __shared__ short Hs[64 * DIM];  // 16 KB bf16
  const int tid = threadIdx.x;
  const int row0 = blockIdx.x * 64;
  const int nrows = min(64, LROWS - row0);

  // Stage H tile -> bf16 LDS + fp8 Hb8 global.
#pragma unroll
  for (int i = 0; i < 4; ++i) {
    const int cid = i * 256 + tid;   // 1024 chunks of 8 elems
    const int r = cid >> 4;          // local row 0..63
    const int cc = (cid & 15) * 8;   // col 0..120
    const int gr = (r < nrows) ? r : 0;
    const float4* src = (const float4*)(H + (size_t)(row0 + gr) * DIM + cc);
    const float4 a = src[0], b = src[1];
    s8v p;
    p[0] = (short)f2bf(a.x); p[1] = (short)f2bf(a.y);
    p[2] = (short)f2bf(a.z); p[3] = (short)f2bf(a.w);
    p[4] = (short)f2bf(b.x); p[5] = (short)f2bf(b.y);
    p[6] = (short)f2bf(b.z); p[7] = (short)f2bf(b.w);
    *(s8v*)&Hs[cid * 8] = p;
    if (r < nrows) {
      unsigned d0 = 0, d1 = 0;
      d0 = __builtin_amdgcn_cvt_pk_fp8_f32(a.x, a.y, d0, false);
      d0 = __builtin_amdgcn_cvt_pk_fp8_f32(a.z, a.w, d0, true);
      d1 = __builtin_amdgcn_cvt_pk_fp8_f32(b.x, b.y, d1, false);
      d1 = __builtin_amdgcn_cvt_pk_fp8_f32(b.z, b.w, d1, true);
      i32x2 pk; pk[0] = (int)d0; pk[1] = (int)d1;
      *(i32x2*)(Hb8 + (size_t)(row0 + r) * DIM + cc) = pk;
    }
  }
  __syncthreads();

  const int lane = tid & 63;
  const int wv = tid >> 6;
  const int col0 = wv * 32;
  const int lr = lane & 15;
  const int lg = lane >> 4;

  s8v bfrag[2][4];
#pragma unroll
  for (int nt = 0; nt < 2; ++nt)
#pragma unroll
    for (int kk = 0; kk < 4; ++kk)
      bfrag[nt][kk] =
          *(const s8v*)(Mt + (col0 + nt * 16 + lr) * DIM + kk * 32 + lg * 8);

  f32x4 acc[4][2];
#pragma unroll
  for (int rt = 0; rt < 4; ++rt)
#pragma unroll
    for (int nt = 0; nt < 2; ++nt)
      acc[rt][nt] = (f32x4){0.f, 0.f, 0.f, 0.f};

#pragma unroll
  for (int rt = 0; rt < 4; ++rt) {
#pragma unroll
    for (int kk = 0; kk < 4; ++kk) {
      const s8v afrag =
          *(const s8v*)&Hs[(rt * 16 + lr) * DIM + kk * 32 + lg * 8];
#pragma unroll
      for (int nt = 0; nt < 2; ++nt)
        acc[rt][nt] = __builtin_amdgcn_mfma_f32_16x16x32_bf16(
            afrag, bfrag[nt][kk], acc[rt][nt], 0, 0, 0);
    }
  }

#pragma unroll
  for (int rt = 0; rt < 4; ++rt)
#pragma unroll
    for (int nt = 0; nt < 2; ++nt)
#pragma unroll
      for (int i = 0; i < 4; ++i) {
        const int r = rt * 16 + lg * 4 + i;
        if (r < nrows)
          G[(size_t)(row0 + r) * DIM + col0 + nt * 16 + lr] = acc[rt][nt][i];
      }
}

// ---------------------------------------------------------------------------
// Kernel C: sim[l,k] = <G[l], fp8 Hb8[idx]> ; softmax + mix + norm + COO.
// Gathered rows are fp8 (128 B = 1 cache line, 6.4 MB footprint ~ L2-hot).
// ---------------------------------------------------------------------------
__global__ __launch_bounds__(256) void attn_kernel(
    const float* __restrict__ G, const unsigned char* __restrict__ Hb8,
    const float* __restrict__ mixp, const float* __restrict__ knn_w,
    const int* __restrict__ knn_idx,
    float* __restrict__ vals, float* __restrict__ rows,
    float* __restrict__ cols) {
  const int tid = threadIdx.x;
  const int k = tid & 31;
  const int rloc = tid >> 5;
  const int l = blockIdx.x * 8 + rloc;

  const int o = l * KNN + k;
  const int idx = knn_idx[o];

  const i32x4* k16 = (const i32x4*)(Hb8 + (size_t)idx * DIM);  // 8 x 16B
  const float4* g4 = (const float4*)(G + (size_t)l * DIM);

  float acc = 0.f;
#pragma unroll
  for (int j = 0; j < 8; ++j) {        // 8 chunks of 16 fp8 elems
    const i32x4 c = k16[j];
#pragma unroll
    for (int d = 0; d < 4; ++d) {      // 4 fp8 per dword
      const f32x2 lo = __builtin_amdgcn_cvt_pk_f32_fp8((unsigned)c[d], false);
      const f32x2 hi = __builtin_amdgcn_cvt_pk_f32_fp8((unsigned)c[d], true);
      const float4 g = g4[4 * j + d];
      acc = fmaf(g.x, lo[0], acc);
      acc = fmaf(g.y, lo[1], acc);
      acc = fmaf(g.z, hi[0], acc);
      acc = fmaf(g.w, hi[1], acc);
    }
  }
  const float sim = acc * TAU_INV;

  float m = sim;
#pragma unroll
  for (int off = 16; off > 0; off >>= 1)
    m = fmaxf(m, __shfl_xor(m, off, 32));
  const float e = expf(sim - m);
  float s = e;
#pragma unroll
  for (int off = 16; off > 0; off >>= 1)
    s += __shfl_xor(s, off, 32);
  const float A = e / s;

  const float beta = 1.0f / (1.0f + expf(-mixp[0]));
  float w = (1.0f - beta) * knn_w[o] + beta * A;

  float ws = w;
#pragma unroll
  for (int off = 16; off > 0; off >>= 1)
    ws += __shfl_xor(ws, off, 32);
  const float v = w / (ws + EPS_NORM);

  vals[o] = v;
  rows[o] = (float)l;
  cols[o] = (float)idx;
}

extern "C" void kernel_launch(void* const* d_in, const int* in_sizes, int n_in,
                              void* d_out, int out_size, void* d_ws, size_t ws_size,
                              hipStream_t stream) {
  const float* H = (const float*)d_in[0];
  const float* Wq = (const float*)d_in[1];
  const float* Wk = (const float*)d_in[2];
  const float* mix = (const float*)d_in[3];
  const float* knn_w = (const float*)d_in[4];
  const int* knn_idx = (const int*)d_in[5];

  unsigned char* Hb8 = (unsigned char*)d_ws;                       // 6.4 MB
  float* G = (float*)((char*)d_ws + (size_t)LROWS * DIM);          // 25.6 MB
  unsigned short* Mt =
      (unsigned short*)((char*)d_ws + (size_t)LROWS * DIM * 5);    // 32 KB

  float* out = (float*)d_out;
  float* vals = out;
  float* rowsp = out + (size_t)LROWS * KNN;
  float* colsp = out + 2 * (size_t)LROWS * KNN;

  mmat_kernel<<<DIM, DIM, 0, stream>>>(Wq, Wk, Mt);
  proj_kernel<<<(LROWS + 63) / 64, 256, 0, stream>>>(H, Mt, G, Hb8);
  attn_kernel<<<LROWS / 8, 256, 0, stream>>>(G, Hb8, mix, knn_w, knn_idx,
                                             vals, rowsp, colsp);
}